// Round 1
// baseline (491.799 us; speedup 1.0000x reference)
//
#include <hip/hip_runtime.h>

// out[b,c,h,w] = x[b,c, 2h+o, 2w+p],  (o,p) = divmod(i, 2)
// B=8, C=3, H=W=2048, Ho=Wo=1024.
// Each thread handles 2 consecutive output columns:
//   - one aligned float4 load from the selected input row
//   - select components p and p+2 (p is wave-uniform -> no divergence)
//   - one float2 store.

#define WO_HALF 512          // Wo/2
#define HO      1024
#define W_IN    2048

__global__ __launch_bounds__(256)
void CNN2__57801669869865_kernel(const float* __restrict__ x,
                                 const int* __restrict__ i_ptr,
                                 float* __restrict__ out,
                                 int total_pairs) {
    const int i = i_ptr[0];
    const int o = (i >> 1) & 1;   // row offset within 2x2 block
    const int p = i & 1;          // col offset within 2x2 block

    int idx = blockIdx.x * blockDim.x + threadIdx.x;
    if (idx >= total_pairs) return;

    const int wpair = idx & (WO_HALF - 1);   // which float4 along the row
    const int row   = idx >> 9;              // (b*C + c)*Ho + h
    const int bc    = row >> 10;             // row / 1024
    const int h     = row & (HO - 1);

    // input row 2h+o of image bc; float4 index wpair covers cols 4w..4w+3
    const float4* src = reinterpret_cast<const float4*>(
        x + ((size_t)bc * W_IN + (size_t)(2 * h + o)) * W_IN) + wpair;
    float4 v = *src;

    float2 r;
    r.x = p ? v.y : v.x;
    r.y = p ? v.w : v.z;

    float2* dst = reinterpret_cast<float2*>(out + (size_t)row * 1024) + wpair;
    *dst = r;
}

extern "C" void kernel_launch(void* const* d_in, const int* in_sizes, int n_in,
                              void* d_out, int out_size, void* d_ws, size_t ws_size,
                              hipStream_t stream) {
    const float* x = (const float*)d_in[0];
    const int* ip  = (const int*)d_in[1];
    float* out     = (float*)d_out;

    const int total_pairs = 8 * 3 * HO * WO_HALF;  // 12,582,912
    const int block = 256;
    const int grid = (total_pairs + block - 1) / block;

    CNN2__57801669869865_kernel<<<grid, block, 0, stream>>>(x, ip, out, total_pairs);
}